// Round 10
// baseline (123.797 us; speedup 1.0000x reference)
//
#include <hip/hip_runtime.h>
#include <hip/hip_bf16.h>
#include <stdint.h>

// Problem constants (fixed by the reference)
#define B_DIM   128
#define N_DIM   36
#define C_DIM   1024
#define KNB     16
#define NKER    8
#define OUTD    1024
#define BN_NODES (B_DIM * N_DIM)     // 4608
#define E_EDGES  (BN_NODES * KNB)    // 73728
#define PI_F 3.14159265358979323846f

// GEMM tiling (R8-verified): 64x128 tile, BK=64, dbuf, XOR swizzle.
// R10: A is staged fp32 -> register cvt -> ds_write (kills the fb
// workspace round trip + most of the cast kernel); B stays bf16 DMA.
#define TM 64
#define TN 128
#define BK 64
#define KIT (C_DIM / BK)   // 16
#define CLP 136            // epilogue C-tile LDS leading dim
#define A_OFF(p) ((p) * TM * BK)                // 0 / 4096 (shorts)
#define B_OFF(p) (2 * TM * BK + (p) * TN * BK)  // 8192 / 16384 (shorts)

typedef __attribute__((ext_vector_type(8))) short bf16x8;   // 8 bf16 = 4 VGPRs
typedef __attribute__((ext_vector_type(4))) float floatx4;  // MFMA C/D frag

struct alignas(8)  U16x4 { unsigned short x, y, z, w; };
struct alignas(16) U16x8 { U16x4 lo, hi; };

__device__ __forceinline__ unsigned short f2bf(float f) {
  union { float f; uint32_t u; } v; v.f = f;
  uint32_t u = v.u;
  return (unsigned short)((u + 0x7fffu + ((u >> 16) & 1u)) >> 16);  // RNE
}
__device__ __forceinline__ float bf2f_lo(uint32_t pair) {
  union { uint32_t u; float f; } v; v.u = pair << 16;
  return v.f;
}
__device__ __forceinline__ float bf2f_hi(uint32_t pair) {
  union { uint32_t u; float f; } v; v.u = pair & 0xffff0000u;
  return v.f;
}

// async global -> LDS, 16B per lane (global_load_lds_dwordx4).
__device__ __forceinline__ void gload16(const void* g, void* l) {
  __builtin_amdgcn_global_load_lds((__attribute__((address_space(1))) void*)(g),
                                   (__attribute__((address_space(3))) void*)(l),
                                   16, 0, 0);
}

// ---------------------------------------------------------------------------
// Kernel 1: cast conv_w (fp32) to bf16 — tiny (4.2 MB read, 2.1 MB write)
// ---------------------------------------------------------------------------
__global__ __launch_bounds__(256)
void cast_wb(const float* __restrict__ cw,       // [1024*1024]
             unsigned short* __restrict__ wb)
{
  int tid = blockIdx.x * 256 + threadIdx.x;      // 262144 float4 groups
  float4 v = ((const float4*)cw)[tid];
  U16x4 o = { f2bf(v.x), f2bf(v.y), f2bf(v.z), f2bf(v.w) };
  ((U16x4*)wb)[tid] = o;
}

// ---------------------------------------------------------------------------
// Kernel 2: proj = feats(fp32) @ wb^T  -> bf16, MFMA.
// 64x128 tile, 4 waves 2x2 (32x64), dbuf BK=64.
//  - A: global fp32 -> regs (prefetch distance 1) -> cvt bf16 -> ds_write
//    (gemm is latency-bound, VALUBusy <5%: the cvt rides idle VALU slots)
//  - B: bf16 DMA (global_load_lds dwordx4), XOR-swizzled global columns
//  - one __syncthreads per iter; LDS-staged coalesced epilogue
// ---------------------------------------------------------------------------
__global__ __launch_bounds__(256)
void gemm_bt(const float* __restrict__ Af,       // [4608][1024] fp32 feats
             const unsigned short* __restrict__ Bt,  // [1024][1024] bf16
             unsigned short* __restrict__ D)     // [4608][1024] bf16
{
  __shared__ unsigned short smem[2 * TM * BK + 2 * TN * BK];  // 48 KB

  const int tid  = threadIdx.x;
  const int lane = tid & 63;
  const int wave = tid >> 6;
  const int wm   = wave >> 1;       // wave row (0..1) -> 32 rows each
  const int wn   = wave & 1;        // wave col (0..1) -> 64 cols each
  const int row0 = blockIdx.x * TM;
  const int col0 = blockIdx.y * TN;

  const int q  = lane >> 4;         // quad
  const int lr = lane & 15;

  floatx4 acc[2][4] = {};

  // A staging: 64 rows x 8 bf16-chunks (16B) = 512 chunks; thread t does
  // chunks c = t, t+256. LDS chunk (row,qc) holds global cols (qc^(row&7))*8..+7
  // B staging: 128x8 chunks = 1024; DMA, LDS addr = c*16 (DMA constraint).
  int offAf[2], ldsA[2];
#pragma unroll
  for (int i = 0; i < 2; ++i) {
    int c = tid + 256 * i, row = c >> 3, qc = c & 7;
    offAf[i] = (row0 + row) * C_DIM + (qc ^ (row & 7)) * 8;   // fp32 elements
    ldsA[i]  = c * 8;                                         // shorts
  }
  int offB[4];
#pragma unroll
  for (int i = 0; i < 4; ++i) {
    int c = tid + 256 * i, row = c >> 3, qc = c & 7;
    offB[i] = (col0 + row) * C_DIM + (qc ^ (row & 7)) * 8;
  }

  float4 aReg[2][2];   // [chunk][half of 8 floats]

#define LDA(T) do {                                                          \
    _Pragma("unroll") for (int i = 0; i < 2; ++i) {                          \
      aReg[i][0] = *(const float4*)(Af + offAf[i] + (T) * BK);               \
      aReg[i][1] = *(const float4*)(Af + offAf[i] + (T) * BK + 4);           \
    }                                                                        \
  } while (0)

#define STA(P) do {                                                          \
    _Pragma("unroll") for (int i = 0; i < 2; ++i) {                          \
      U16x8 o;                                                               \
      o.lo.x = f2bf(aReg[i][0].x); o.lo.y = f2bf(aReg[i][0].y);              \
      o.lo.z = f2bf(aReg[i][0].z); o.lo.w = f2bf(aReg[i][0].w);              \
      o.hi.x = f2bf(aReg[i][1].x); o.hi.y = f2bf(aReg[i][1].y);              \
      o.hi.z = f2bf(aReg[i][1].z); o.hi.w = f2bf(aReg[i][1].w);              \
      *(U16x8*)&smem[A_OFF(P) + ldsA[i]] = o;                                \
    }                                                                        \
  } while (0)

#define DMAB(T, P) do {                                                      \
    _Pragma("unroll") for (int i = 0; i < 4; ++i)                            \
      gload16(Bt + offB[i] + (T) * BK,                                       \
              &smem[B_OFF(P) + (tid + 256 * i) * 8]);                        \
  } while (0)

  // prologue: tile 0 -> regs -> buf 0; B tile 0 -> DMA buf 0
  LDA(0);
  DMAB(0, 0);
  STA(0);

  for (int t = 0; t < KIT; ++t) {
    const int p = t & 1;
    __syncthreads();                  // drains B DMA(t) + A ds_writes(t)
    if (t + 1 < KIT) { LDA(t + 1); DMAB(t + 1, 1 - p); }

    const int aBase = A_OFF(p);
    const int bBase = B_OFF(p);
#pragma unroll
    for (int kc = 0; kc < 2; ++kc) {
      // frag (row r, chunk kc*4+q) at swizzled chunk ((kc*4+q)^(lr&7))
      const int sc = ((kc * 4 + q) ^ (lr & 7)) * 8;
      bf16x8 af[2], bfr[4];
#pragma unroll
      for (int i = 0; i < 2; ++i)
        af[i]  = *(const bf16x8*)&smem[aBase + (wm * 32 + i * 16 + lr) * BK + sc];
#pragma unroll
      for (int j = 0; j < 4; ++j)
        bfr[j] = *(const bf16x8*)&smem[bBase + (wn * 64 + j * 16 + lr) * BK + sc];
#pragma unroll
      for (int i = 0; i < 2; ++i)
#pragma unroll
        for (int j = 0; j < 4; ++j)
          acc[i][j] = __builtin_amdgcn_mfma_f32_16x16x32_bf16(
              af[i], bfr[j], acc[i][j], 0, 0, 0);
    }
    // hand tile t+1's A into buffer 1-p (safe: all waves passed the top
    // barrier after finishing their reads of 1-p at iteration t-1)
    if (t + 1 < KIT) STA(1 - p);
  }
#undef LDA
#undef STA
#undef DMAB

  // ---- epilogue: stage C tile (64x128 bf16) in LDS, coalesced stores ----
  __syncthreads();
#pragma unroll
  for (int i = 0; i < 2; ++i)
#pragma unroll
    for (int j = 0; j < 4; ++j)
#pragma unroll
      for (int r = 0; r < 4; ++r)
        smem[(wm * 32 + i * 16 + q * 4 + r) * CLP + wn * 64 + j * 16 + lr] =
            f2bf(acc[i][j][r]);
  __syncthreads();
  // full tile = 64 rows x 16 chunks = 1024; thread t does 4
#pragma unroll
  for (int i = 0; i < 4; ++i) {
    int c = tid + 256 * i;
    int row = c >> 4, qc = c & 15;
    *(uint4*)&D[(size_t)(row0 + row) * OUTD + col0 + qc * 8] =
        *(const uint4*)&smem[row * CLP + qc * 8];
  }
}

// ---------------------------------------------------------------------------
// Kernel 3: fused edge-weight + aggregate, 2 nodes per block (R8-verified).
// ---------------------------------------------------------------------------
__global__ __launch_bounds__(256)
void agg_fused(const unsigned short* __restrict__ proj,  // [BN][1024] bf16
               const float* __restrict__ centre,         // [BN][2]
               const int*   __restrict__ nbr,            // [BN][16]
               const float* __restrict__ gw,             // [E]
               const float* __restrict__ mrho,
               const float* __restrict__ mth,
               const float* __restrict__ prho,
               const float* __restrict__ pth,
               float* __restrict__ out)                  // [BN][1024] fp32
{
  __shared__ int   idx[2][KNB];
  __shared__ float nxy[2][KNB][2];
  __shared__ float cxy[2][2];
  __shared__ float wk[2][KNB][NKER];
  __shared__ float scl[2][KNB];
  __shared__ float ew[2][NKER][KNB];

  const int n0   = blockIdx.x * 2;
  const int t    = threadIdx.x;
  const int half = t >> 7;
  const int u    = t & 127;

  if (t < 32) {
    int h = t >> 4, j = t & 15;
    int m = nbr[(n0 + h) * KNB + j];
    idx[h][j] = m;
    nxy[h][j][0] = centre[2 * m];
    nxy[h][j][1] = centre[2 * m + 1];
  } else if (t < 34) {
    int h = t - 32;
    cxy[h][0] = centre[2 * (n0 + h)];
    cxy[h][1] = centre[2 * (n0 + h) + 1];
  }
  __syncthreads();

  {                                    // 2 nodes x 16 edges x 8 kernels
    int j = u >> 3, k = u & 7;
    float cx = cxy[half][0] - nxy[half][j][0];
    float cy = cxy[half][1] - nxy[half][j][1];
    float rho   = sqrtf(cx * cx + cy * cy);
    float theta = atan2f(cx, cy);      // jnp.arctan2(coord_x, coord_y)
    float dr = rho - mrho[k];
    float pr = prho[k];
    float w_r = expf(-0.5f * dr * dr / (1e-14f + pr * pr));
    float fa = fabsf(theta - mth[k]);
    float sa = fabsf(2.0f * PI_F - fa);
    float mm = fminf(fa, sa);
    float pt = pth[k];
    float w_t = expf(-0.5f * mm * mm / (1e-14f + pt * pt));
    float ww = w_r * w_t;
    wk[half][j][k] = (ww != ww) ? 0.f : ww;   // NaN guard (reference parity)
  }
  __syncthreads();

  if (u < KNB) {
    float s = 0.f;
#pragma unroll
    for (int k = 0; k < NKER; ++k) s += wk[half][u][k];
    scl[half][u] = gw[(n0 + half) * KNB + u] / s;
  }
  __syncthreads();

  {
    int j = u >> 3, k = u & 7;
    ew[half][k][j] = wk[half][j][k] * scl[half][j];
  }
  __syncthreads();

  // main aggregate: thread u -> channels 8u..8u+7 (kernel block k = u/16)
  const int n = n0 + half;
  const int k = u >> 4;
  float a[8] = {0.f, 0.f, 0.f, 0.f, 0.f, 0.f, 0.f, 0.f};
#pragma unroll
  for (int j = 0; j < KNB; ++j) {
    float wv = ew[half][k][j];
    uint4 v = *(const uint4*)&proj[(size_t)idx[half][j] * OUTD + u * 8];
    a[0] += wv * bf2f_lo(v.x);  a[1] += wv * bf2f_hi(v.x);
    a[2] += wv * bf2f_lo(v.y);  a[3] += wv * bf2f_hi(v.y);
    a[4] += wv * bf2f_lo(v.z);  a[5] += wv * bf2f_hi(v.z);
    a[6] += wv * bf2f_lo(v.w);  a[7] += wv * bf2f_hi(v.w);
  }
  float4 r0, r1;
  r0.x = fmaxf(a[0], 0.f); r0.y = fmaxf(a[1], 0.f);
  r0.z = fmaxf(a[2], 0.f); r0.w = fmaxf(a[3], 0.f);
  r1.x = fmaxf(a[4], 0.f); r1.y = fmaxf(a[5], 0.f);
  r1.z = fmaxf(a[6], 0.f); r1.w = fmaxf(a[7], 0.f);
  float* o = out + (size_t)n * OUTD + u * 8;
  *(float4*)(o)     = r0;
  *(float4*)(o + 4) = r1;
}

// ---------------------------------------------------------------------------
extern "C" void kernel_launch(void* const* d_in, const int* in_sizes, int n_in,
                              void* d_out, int out_size, void* d_ws, size_t ws_size,
                              hipStream_t stream)
{
  const float* feats  = (const float*)d_in[0];   // [128,36,1024]
  const float* centre = (const float*)d_in[1];   // [128,36,2]
  const int*   nbr    = (const int*)  d_in[2];   // [4608,16]
  const float* gw     = (const float*)d_in[3];   // [73728,1]
  const float* mrho   = (const float*)d_in[4];
  const float* mth    = (const float*)d_in[5];
  const float* prho   = (const float*)d_in[6];
  const float* pth    = (const float*)d_in[7];
  const float* cw     = (const float*)d_in[8];   // [8,128,1024] == [1024,1024]
  float* out = (float*)d_out;

  // workspace layout (11.5 MB)
  char* ws = (char*)d_ws;
  unsigned short* wb   = (unsigned short*)(ws);              // 2,097,152 B
  unsigned short* proj = (unsigned short*)(ws + 2097152);    // 9,437,184 B

  cast_wb<<<dim3((C_DIM * OUTD) / 4 / 256), dim3(256), 0, stream>>>(cw, wb);
  gemm_bt<<<dim3(BN_NODES / TM, OUTD / TN), dim3(256), 0, stream>>>(feats, wb, proj);
  agg_fused<<<dim3(BN_NODES / 2), dim3(256), 0, stream>>>(
      proj, centre, nbr, gw, mrho, mth, prho, pth, out);
}